// Round 1
// baseline (359.626 us; speedup 1.0000x reference)
//
#include <hip/hip_runtime.h>
#include <math.h>

#define NPTS 8192
#define NB 2
#define CCH 128
#define KNN 16

// ---------------- K0: transpose x [B,C,N] -> xT [B,N,C] ----------------
__global__ __launch_bounds__(256) void k_transpose(const float* __restrict__ x,
                                                   float* __restrict__ xT) {
  __shared__ float t[32][65];
  int blk = blockIdx.x;
  int b = blk >> 9;             // 512 tiles per batch: 4 c-tiles x 128 n-tiles
  int rem = blk & 511;
  int c0 = (rem >> 7) << 5;
  int n0 = (rem & 127) << 6;
  const float* xb = x + (size_t)b * CCH * NPTS;
  float* xTb = xT + (size_t)b * NPTS * CCH;
  int nj = threadIdx.x & 63, ci = threadIdx.x >> 6;
#pragma unroll
  for (int i = 0; i < 8; ++i) {
    int c = ci * 8 + i;
    t[c][nj] = xb[(size_t)(c0 + c) * NPTS + n0 + nj];
  }
  __syncthreads();
  int cl = threadIdx.x & 31, nl = threadIdx.x >> 5;
#pragma unroll
  for (int i = 0; i < 8; ++i) {
    int n = nl * 8 + i;
    xTb[(size_t)(n0 + n) * CCH + c0 + cl] = t[cl][n];
  }
}

// ---------------- K1: KNN, wave-per-query, lane-distributed sorted top-16 ----
__global__ __launch_bounds__(512) void k_knn(const float* __restrict__ pos,
                                             int* __restrict__ nn_idx,
                                             float* __restrict__ nn_w) {
  __shared__ float4 cpos[2048];                 // 32 KB chunk of candidates
  const int b = blockIdx.x >> 10;               // 1024 blocks per batch
  const int q = ((blockIdx.x & 1023) << 3) + (threadIdx.x >> 6);
  const int lane = threadIdx.x & 63;
  const float* px = pos + (size_t)b * 3 * NPTS;
  const float* py = px + NPTS;
  const float* pz = py + NPTS;
  const float qx = px[q], qy = py[q], qz = pz[q];
  float bd = 3.4e38f;   // lane<16: sorted (ascending) top-16 squared distances
  int bi = 0;
  float T = 3.4e38f;    // current 16th (wave-uniform value)
  for (int ch = 0; ch < 4; ++ch) {
    __syncthreads();
    for (int i = threadIdx.x; i < 2048; i += 512) {
      int j = (ch << 11) + i;
      cpos[i] = make_float4(px[j], py[j], pz[j], 0.f);
    }
    __syncthreads();
    for (int t = 0; t < 32; ++t) {
      float4 cp = cpos[(t << 6) + lane];
      float dx = qx - cp.x, dy = qy - cp.y, dz = qz - cp.z;
      float d2 = dx * dx + dy * dy + dz * dz;
      unsigned long long m = __ballot(d2 < T);
      while (m) {
        int l = __builtin_ctzll(m);
        m &= m - 1;
        float v = __shfl(d2, l);          // uniform across wave
        if (v < T) {                      // re-check against tightened T
          int vi = (ch << 11) + (t << 6) + l;
          bool gt = (lane < KNN) && (bd > v);     // strictly greater -> shift up
          float ud = __shfl_up(bd, 1);            // cross-lane ops outside divergence
          int ui = __shfl_up(bi, 1);
          int pg = __shfl_up(gt ? 1 : 0, 1);
          if (gt) {
            bool first = (lane == 0) || (pg == 0);
            bd = first ? v : ud;
            bi = first ? vi : ui;
          }
          T = __shfl(bd, 15);
        }
      }
    }
  }
  // softmax over the 16 neighbors (lane 0 holds the min distance = self)
  float d = fmaxf(sqrtf(bd), 1e-6f);
  float logit = -d * 5.0f;                 // 1/TAU = 5
  float mx = __shfl(logit, 0);
  float e = (lane < KNN) ? __expf(logit - mx) : 0.f;
  float s = e;
  s += __shfl_xor(s, 1);
  s += __shfl_xor(s, 2);
  s += __shfl_xor(s, 4);
  s += __shfl_xor(s, 8);
  if (lane < KNN) {
    size_t o = ((size_t)b * NPTS + q) * KNN + lane;
    nn_idx[o] = bi;
    nn_w[o] = e / s;
  }
}

// ---------------- K2: gather+aggregate + GEMM1 (fuse[256] x w1^T) + BN1 stats -
__global__ __launch_bounds__(256) void k_gemm1(const float* __restrict__ xT,
                                               const int* __restrict__ nn_idx,
                                               const float* __restrict__ nn_w,
                                               const float* __restrict__ w1,
                                               float* __restrict__ h_pre,
                                               float* __restrict__ stats1) {
  __shared__ float agg[64][132];
  __shared__ int sidx[1024];
  __shared__ float sw[1024];
  __shared__ float sred[256];
  int b = blockIdx.x >> 7;
  int r0 = (blockIdx.x & 127) << 6;
  const float* xTb = xT + (size_t)b * NPTS * CCH;
  sred[threadIdx.x] = 0.f;
  for (int i = threadIdx.x; i < 1024; i += 256) {
    size_t o = ((size_t)b * NPTS + r0) * KNN + i;
    sidx[i] = nn_idx[o];
    sw[i] = nn_w[o];
  }
  __syncthreads();
  {  // aggregation: thread = (row, 32-channel group)
    int r = threadIdx.x >> 2, cg = threadIdx.x & 3;
    float acc[32];
#pragma unroll
    for (int i = 0; i < 32; ++i) acc[i] = 0.f;
    for (int k = 0; k < KNN; ++k) {
      int idx = sidx[(r << 4) + k];
      float w = sw[(r << 4) + k];
      const float4* src = (const float4*)(xTb + (size_t)idx * CCH + (cg << 5));
#pragma unroll
      for (int u = 0; u < 8; ++u) {
        float4 v = src[u];
        acc[u * 4 + 0] += w * v.x;
        acc[u * 4 + 1] += w * v.y;
        acc[u * 4 + 2] += w * v.z;
        acc[u * 4 + 3] += w * v.w;
      }
    }
#pragma unroll
    for (int u = 0; u < 8; ++u)
      *(float4*)&agg[r][(cg << 5) + (u << 2)] =
          make_float4(acc[u * 4], acc[u * 4 + 1], acc[u * 4 + 2], acc[u * 4 + 3]);
  }
  __syncthreads();
  // GEMM: thread = (rg, og) computes rows {rg, rg+16, rg+32, rg+48} x outs og*8..+8
  int rg = threadIdx.x >> 4, og = threadIdx.x & 15;
  float accg[4][8];
#pragma unroll
  for (int i = 0; i < 4; ++i)
#pragma unroll
    for (int j = 0; j < 8; ++j) accg[i][j] = 0.f;
  for (int cq = 0; cq < 64; ++cq) {
    int c = cq << 2;
    float4 a[4];
    if (c < 128) {
#pragma unroll
      for (int i = 0; i < 4; ++i)
        a[i] = *(const float4*)(xTb + (size_t)(r0 + rg + (i << 4)) * CCH + c);
    } else {
#pragma unroll
      for (int i = 0; i < 4; ++i)
        a[i] = *(const float4*)&agg[rg + (i << 4)][c - 128];
    }
#pragma unroll
    for (int j = 0; j < 8; ++j) {
      float4 wv = *(const float4*)(w1 + (size_t)((og << 3) + j) * 256 + c);
#pragma unroll
      for (int i = 0; i < 4; ++i)
        accg[i][j] += a[i].x * wv.x + a[i].y * wv.y + a[i].z * wv.z + a[i].w * wv.w;
    }
  }
#pragma unroll
  for (int i = 0; i < 4; ++i) {
    int row = r0 + rg + (i << 4);
    float* dst = h_pre + ((size_t)b * NPTS + row) * CCH + (og << 3);
    *(float4*)dst = make_float4(accg[i][0], accg[i][1], accg[i][2], accg[i][3]);
    *(float4*)(dst + 4) = make_float4(accg[i][4], accg[i][5], accg[i][6], accg[i][7]);
  }
#pragma unroll
  for (int j = 0; j < 8; ++j) {
    float ps = accg[0][j] + accg[1][j] + accg[2][j] + accg[3][j];
    float pq = accg[0][j] * accg[0][j] + accg[1][j] * accg[1][j] +
               accg[2][j] * accg[2][j] + accg[3][j] * accg[3][j];
    atomicAdd(&sred[(og << 3) + j], ps);
    atomicAdd(&sred[128 + (og << 3) + j], pq);
  }
  __syncthreads();
  atomicAdd(&stats1[threadIdx.x], sred[threadIdx.x]);
}

// ---------------- K4: BN1+ReLU + GEMM2 + BN2 stats ----------------
__global__ __launch_bounds__(256) void k_gemm2(const float* __restrict__ h_pre,
                                               const float* __restrict__ stats1,
                                               const float* __restrict__ g1,
                                               const float* __restrict__ b1,
                                               const float* __restrict__ w2,
                                               float* __restrict__ y_pre,
                                               float* __restrict__ stats2) {
  __shared__ float hl[64][132];
  __shared__ float sred[256];
  int b = blockIdx.x >> 7;
  int r0 = (blockIdx.x & 127) << 6;
  sred[threadIdx.x] = 0.f;
  {
    int c = threadIdx.x & 127;
    float sm = stats1[c] * (1.f / 16384.f);
    float sq = stats1[128 + c] * (1.f / 16384.f);
    float var = fmaxf(sq - sm * sm, 0.f);
    float sc = g1[c] * rsqrtf(var + 1e-5f);
    float sh = b1[c] - sm * sc;
    for (int r = threadIdx.x >> 7; r < 64; r += 2) {
      float v = h_pre[((size_t)b * NPTS + r0 + r) * CCH + c];
      hl[r][c] = fmaxf(v * sc + sh, 0.f);
    }
  }
  __syncthreads();
  int rg = threadIdx.x >> 4, og = threadIdx.x & 15;
  float accg[4][8];
#pragma unroll
  for (int i = 0; i < 4; ++i)
#pragma unroll
    for (int j = 0; j < 8; ++j) accg[i][j] = 0.f;
  for (int cq = 0; cq < 32; ++cq) {
    int c = cq << 2;
    float4 a[4];
#pragma unroll
    for (int i = 0; i < 4; ++i) a[i] = *(const float4*)&hl[rg + (i << 4)][c];
#pragma unroll
    for (int j = 0; j < 8; ++j) {
      float4 wv = *(const float4*)(w2 + (size_t)((og << 3) + j) * CCH + c);
#pragma unroll
      for (int i = 0; i < 4; ++i)
        accg[i][j] += a[i].x * wv.x + a[i].y * wv.y + a[i].z * wv.z + a[i].w * wv.w;
    }
  }
#pragma unroll
  for (int i = 0; i < 4; ++i) {
    int row = r0 + rg + (i << 4);
    float* dst = y_pre + ((size_t)b * NPTS + row) * CCH + (og << 3);
    *(float4*)dst = make_float4(accg[i][0], accg[i][1], accg[i][2], accg[i][3]);
    *(float4*)(dst + 4) = make_float4(accg[i][4], accg[i][5], accg[i][6], accg[i][7]);
  }
#pragma unroll
  for (int j = 0; j < 8; ++j) {
    float ps = accg[0][j] + accg[1][j] + accg[2][j] + accg[3][j];
    float pq = accg[0][j] * accg[0][j] + accg[1][j] * accg[1][j] +
               accg[2][j] * accg[2][j] + accg[3][j] * accg[3][j];
    atomicAdd(&sred[(og << 3) + j], ps);
    atomicAdd(&sred[128 + (og << 3) + j], pq);
  }
  __syncthreads();
  atomicAdd(&stats2[threadIdx.x], sred[threadIdx.x]);
}

// ---------------- K6: SE pool: s_sum[b][c] = sum_n relu(bn2(y_pre)) ----------
__global__ __launch_bounds__(256) void k_sepool(const float* __restrict__ y_pre,
                                                const float* __restrict__ stats2,
                                                const float* __restrict__ g2,
                                                const float* __restrict__ b2,
                                                float* __restrict__ s_sum) {
  __shared__ float red[256];
  int b = blockIdx.x >> 5;
  int r0 = (blockIdx.x & 31) << 8;
  int c = threadIdx.x & 127, half = threadIdx.x >> 7;
  float sm = stats2[c] * (1.f / 16384.f);
  float sq = stats2[128 + c] * (1.f / 16384.f);
  float var = fmaxf(sq - sm * sm, 0.f);
  float sc = g2[c] * rsqrtf(var + 1e-5f);
  float sh = b2[c] - sm * sc;
  float acc = 0.f;
  for (int r = half; r < 256; r += 2) {
    float v = y_pre[((size_t)b * NPTS + r0 + r) * CCH + c];
    acc += fmaxf(v * sc + sh, 0.f);
  }
  red[threadIdx.x] = acc;
  __syncthreads();
  if (half == 0) atomicAdd(&s_sum[b * CCH + c], red[c] + red[128 + c]);
}

// ---------------- K7: SE gate (tiny) ----------------
__global__ __launch_bounds__(128) void k_segate(const float* __restrict__ s_sum,
                                                const float* __restrict__ fc1w,
                                                const float* __restrict__ fc1b,
                                                const float* __restrict__ fc2w,
                                                const float* __restrict__ fc2b,
                                                float* __restrict__ gate) {
  __shared__ float s[128];
  __shared__ float hid[8];
  int b = blockIdx.x, t = threadIdx.x;
  s[t] = s_sum[b * CCH + t] * (1.f / 8192.f);
  __syncthreads();
  if (t < 8) {
    float a = fc1b[t];
    for (int c = 0; c < 128; ++c) a += s[c] * fc1w[t * 128 + c];
    hid[t] = fmaxf(a, 0.f);
  }
  __syncthreads();
  float a = fc2b[t];
#pragma unroll
  for (int j = 0; j < 8; ++j) a += hid[j] * fc2w[t * 8 + j];
  gate[b * CCH + t] = 1.f / (1.f + __expf(-a));
}

// ---------------- K8: bn2+relu+gate + residual + transpose to [B,C,N] --------
__global__ __launch_bounds__(256) void k_out(const float* __restrict__ x,
                                             const float* __restrict__ y_pre,
                                             const float* __restrict__ stats2,
                                             const float* __restrict__ g2,
                                             const float* __restrict__ b2,
                                             const float* __restrict__ gate,
                                             float* __restrict__ out) {
  __shared__ float t[64][129];
  int b = blockIdx.x >> 7;
  int n0 = (blockIdx.x & 127) << 6;
  {
    int c = threadIdx.x & 127;
    float sm = stats2[c] * (1.f / 16384.f);
    float sq = stats2[128 + c] * (1.f / 16384.f);
    float var = fmaxf(sq - sm * sm, 0.f);
    float sc = g2[c] * rsqrtf(var + 1e-5f);
    float sh = b2[c] - sm * sc;
    float gt = gate[b * CCH + c];
    for (int r = threadIdx.x >> 7; r < 64; r += 2) {
      float v = y_pre[((size_t)b * NPTS + n0 + r) * CCH + c];
      t[r][c] = fmaxf(v * sc + sh, 0.f) * gt;
    }
  }
  __syncthreads();
  int nl = threadIdx.x & 63, cg = threadIdx.x >> 6;
  for (int cc = cg; cc < CCH; cc += 4) {
    size_t o = ((size_t)b * CCH + cc) * NPTS + n0 + nl;
    out[o] = x[o] + t[nl][cc];
  }
}

extern "C" void kernel_launch(void* const* d_in, const int* in_sizes, int n_in,
                              void* d_out, int out_size, void* d_ws, size_t ws_size,
                              hipStream_t stream) {
  const float* x = (const float*)d_in[0];
  const float* pos = (const float*)d_in[1];
  const float* w1 = (const float*)d_in[2];
  const float* g1 = (const float*)d_in[3];
  const float* b1 = (const float*)d_in[4];
  const float* w2 = (const float*)d_in[5];
  const float* g2 = (const float*)d_in[6];
  const float* b2 = (const float*)d_in[7];
  const float* fc1w = (const float*)d_in[8];
  const float* fc1b = (const float*)d_in[9];
  const float* fc2w = (const float*)d_in[10];
  const float* fc2b = (const float*)d_in[11];
  float* out = (float*)d_out;
  char* ws = (char*)d_ws;

  float* xT = (float*)(ws + 0);                   //  8 MB
  int* nn_idx = (int*)(ws + 8388608);             //  2 MB
  float* nn_w = (float*)(ws + 10485760);          //  2 MB
  float* h_pre = (float*)(ws + 12582912);         //  8 MB
  float* y_pre = (float*)(ws + 20971520);         //  8 MB
  float* stats1 = (float*)(ws + 29360128);        //  1 KB  (sum[128], sumsq[128])
  float* stats2 = (float*)(ws + 29361152);        //  1 KB
  float* s_sum = (float*)(ws + 29362176);         //  1 KB
  float* gate = (float*)(ws + 29363200);          //  1 KB

  hipMemsetAsync(ws + 29360128, 0, 4096, stream);

  k_transpose<<<1024, 256, 0, stream>>>(x, xT);
  k_knn<<<2048, 512, 0, stream>>>(pos, nn_idx, nn_w);
  k_gemm1<<<256, 256, 0, stream>>>(xT, nn_idx, nn_w, w1, h_pre, stats1);
  k_gemm2<<<256, 256, 0, stream>>>(h_pre, stats1, g1, b1, w2, y_pre, stats2);
  k_sepool<<<64, 256, 0, stream>>>(y_pre, stats2, g2, b2, s_sum);
  k_segate<<<2, 128, 0, stream>>>(s_sum, fc1w, fc1b, fc2w, fc2b, gate);
  k_out<<<256, 256, 0, stream>>>(x, y_pre, stats2, g2, b2, gate, out);
}

// Round 2
// 291.777 us; speedup vs baseline: 1.2325x; 1.2325x over previous
//
#include <hip/hip_runtime.h>
#include <math.h>

#define NPTS 8192
#define NB 2
#define CCH 128
#define KNN 16

// ---------------- K0: transpose x [B,C,N] -> xT [B,N,C] ----------------
__global__ __launch_bounds__(256) void k_transpose(const float* __restrict__ x,
                                                   float* __restrict__ xT) {
  __shared__ float t[32][65];
  int blk = blockIdx.x;
  int b = blk >> 9;             // 512 tiles per batch: 4 c-tiles x 128 n-tiles
  int rem = blk & 511;
  int c0 = (rem >> 7) << 5;
  int n0 = (rem & 127) << 6;
  const float* xb = x + (size_t)b * CCH * NPTS;
  float* xTb = xT + (size_t)b * NPTS * CCH;
  int nj = threadIdx.x & 63, ci = threadIdx.x >> 6;
#pragma unroll
  for (int i = 0; i < 8; ++i) {
    int c = ci * 8 + i;
    t[c][nj] = xb[(size_t)(c0 + c) * NPTS + n0 + nj];
  }
  __syncthreads();
  int cl = threadIdx.x & 31, nl = threadIdx.x >> 5;
#pragma unroll
  for (int i = 0; i < 8; ++i) {
    int n = nl * 8 + i;
    xTb[(size_t)(n0 + n) * CCH + c0 + cl] = t[cl][n];
  }
}

// ---------------- K1: KNN, 2 queries per wave, scalar drains ----------------
// lanes 0-31: query A (sub = lane), lanes 32-63: query B (sub = lane-32).
// Both halves evaluate the SAME 32 candidates per iteration (LDS broadcast).
// Top-16 (sorted ascending) lives lane-distributed: A in lanes 0-15,
// B in lanes 32-47.

#define SWZI(v, imm) __builtin_amdgcn_ds_swizzle((v), (imm))
#define SWZF(v, imm) __int_as_float(__builtin_amdgcn_ds_swizzle(__float_as_int(v), (imm)))

// bitonic compare-exchange stage within each 32-lane half
#define BSTAGE(K, J, IMM)                                          \
  {                                                                \
    float od = SWZF(sd, IMM);                                      \
    int oi = SWZI(si, IMM);                                        \
    bool up = ((sub & (K)) == 0);                                  \
    bool lower = ((sub & (J)) == 0);                               \
    bool take = lower ? ((sd > od) == up) : ((sd < od) == up);     \
    if (take) { sd = od; si = oi; }                                \
  }

__global__ __launch_bounds__(512, 8) void k_knn(const float* __restrict__ pos,
                                                int* __restrict__ nn_idx,
                                                float* __restrict__ nn_w) {
  __shared__ float4 cpos[2048];                   // 32 KB chunk: (x,y,z,|p|^2)
  const int b = blockIdx.x >> 9;                  // 512 blocks per batch
  const int wid = threadIdx.x >> 6;
  const int lane = threadIdx.x & 63;
  const int sub = lane & 31;
  const int grp = lane >> 5;
  const int q = ((blockIdx.x & 511) << 4) + (wid << 1) + grp;
  const float* px = pos + (size_t)b * 3 * NPTS;
  const float* py = px + NPTS;
  const float* pz = py + NPTS;
  const float qx = px[q], qy = py[q], qz = pz[q];
  const float n2qx = -2.f * qx, n2qy = -2.f * qy, n2qz = -2.f * qz;
  const float qsq = fmaf(qx, qx, fmaf(qy, qy, qz * qz));
  const bool holder = (sub < 16);
  const int addrUp = (lane == 0 ? 0 : (lane - 1)) << 2;   // shfl_up(1) bpermute addr
  const int addrT = ((lane & 32) | 15) << 2;              // group 16th broadcast

  float bd = 3.4e38f;  // holders: sorted ascending top-16 selection distances
  int bi = 0;
  float Tv = 3.4e38f;  // per-lane copy of own group's 16th-smallest

  for (int ch = 0; ch < 4; ++ch) {
    __syncthreads();
    for (int i = threadIdx.x; i < 2048; i += 512) {
      int j = (ch << 11) + i;
      float x = px[j], y = py[j], z = pz[j];
      cpos[i] = make_float4(x, y, z, fmaf(x, x, fmaf(y, y, z * z)));
    }
    __syncthreads();
    int t0 = 0;
    if (ch == 0) {
      // seed: full sort of candidates 0..31 (per 32-lane half) -> top-16 + T
      float4 cp = cpos[sub];
      float sd = fmaf(cp.z, n2qz, fmaf(cp.y, n2qy, fmaf(cp.x, n2qx, cp.w + qsq)));
      int si = sub;
      BSTAGE(2, 1, 0x041F)
      BSTAGE(4, 2, 0x081F)  BSTAGE(4, 1, 0x041F)
      BSTAGE(8, 4, 0x101F)  BSTAGE(8, 2, 0x081F)  BSTAGE(8, 1, 0x041F)
      BSTAGE(16, 8, 0x201F) BSTAGE(16, 4, 0x101F) BSTAGE(16, 2, 0x081F) BSTAGE(16, 1, 0x041F)
      BSTAGE(32, 16, 0x401F) BSTAGE(32, 8, 0x201F) BSTAGE(32, 4, 0x101F) BSTAGE(32, 2, 0x081F) BSTAGE(32, 1, 0x041F)
      bd = holder ? sd : 3.4e38f;
      bi = si;
      Tv = __int_as_float(__builtin_amdgcn_ds_bpermute(addrT, __float_as_int(bd)));
      t0 = 1;
    }
    for (int t = t0; t < 64; ++t) {
      float4 cp = cpos[(t << 5) + sub];
      float d2 = fmaf(cp.z, n2qz, fmaf(cp.y, n2qy, fmaf(cp.x, n2qx, cp.w + qsq)));
      unsigned long long m = __ballot(d2 < Tv);
      if (m) {
        int cb = (ch << 11) + (t << 5);
        unsigned int mA = (unsigned int)m;
        unsigned int mB = (unsigned int)(m >> 32);
        while (mA) {
          int l = __builtin_ctz(mA);
          mA &= mA - 1;
          float v = __int_as_float(__builtin_amdgcn_readlane(__float_as_int(d2), l));
          int vi = cb + l;
          bool gt = (lane < 16) && (bd > v);      // suffix of A's sorted list
          unsigned long long bm = __ballot(gt);
          float ud = __int_as_float(__builtin_amdgcn_ds_bpermute(addrUp, __float_as_int(bd)));
          int ui = __builtin_amdgcn_ds_bpermute(addrUp, bi);
          bool first = (sub == 0) || !(((bm << 1) >> lane) & 1);
          if (gt) {
            bd = first ? v : ud;
            bi = first ? vi : ui;
          }
        }
        while (mB) {
          int l = __builtin_ctz(mB);
          mB &= mB - 1;
          float v = __int_as_float(__builtin_amdgcn_readlane(__float_as_int(d2), l + 32));
          int vi = cb + l;
          bool gt = (lane >= 32) && (lane < 48) && (bd > v);
          unsigned long long bm = __ballot(gt);
          float ud = __int_as_float(__builtin_amdgcn_ds_bpermute(addrUp, __float_as_int(bd)));
          int ui = __builtin_amdgcn_ds_bpermute(addrUp, bi);
          bool first = (sub == 0) || !(((bm << 1) >> lane) & 1);
          if (gt) {
            bd = first ? v : ud;
            bi = first ? vi : ui;
          }
        }
        Tv = __int_as_float(__builtin_amdgcn_ds_bpermute(addrT, __float_as_int(bd)));
      }
    }
  }
  // recompute distance from actual diffs (matches reference), softmax over 16
  float nx = px[bi], ny = py[bi], nz = pz[bi];
  float dx = qx - nx, dy = qy - ny, dz = qz - nz;
  float dd = fmaxf(sqrtf(fmaf(dx, dx, fmaf(dy, dy, dz * dz))), 1e-6f);
  float logit = -dd * 5.0f;                       // 1/TAU = 5
  float mx = logit;
  mx = fmaxf(mx, SWZF(mx, 0x041F));
  mx = fmaxf(mx, SWZF(mx, 0x081F));
  mx = fmaxf(mx, SWZF(mx, 0x101F));
  mx = fmaxf(mx, SWZF(mx, 0x201F));
  float e = __expf(logit - mx);
  float s = e;
  s += SWZF(s, 0x041F);
  s += SWZF(s, 0x081F);
  s += SWZF(s, 0x101F);
  s += SWZF(s, 0x201F);
  if (holder) {
    size_t o = ((size_t)b * NPTS + q) * KNN + sub;
    nn_idx[o] = bi;
    nn_w[o] = e / s;
  }
}

// ---------------- K2: gather+aggregate + GEMM1 (fuse[256] x w1^T) + BN1 stats -
__global__ __launch_bounds__(256) void k_gemm1(const float* __restrict__ xT,
                                               const int* __restrict__ nn_idx,
                                               const float* __restrict__ nn_w,
                                               const float* __restrict__ w1,
                                               float* __restrict__ h_pre,
                                               float* __restrict__ stats1) {
  __shared__ float agg[64][132];
  __shared__ int sidx[1024];
  __shared__ float sw[1024];
  __shared__ float sred[256];
  int b = blockIdx.x >> 7;
  int r0 = (blockIdx.x & 127) << 6;
  const float* xTb = xT + (size_t)b * NPTS * CCH;
  sred[threadIdx.x] = 0.f;
  for (int i = threadIdx.x; i < 1024; i += 256) {
    size_t o = ((size_t)b * NPTS + r0) * KNN + i;
    sidx[i] = nn_idx[o];
    sw[i] = nn_w[o];
  }
  __syncthreads();
  {  // aggregation: thread = (row, 32-channel group)
    int r = threadIdx.x >> 2, cg = threadIdx.x & 3;
    float acc[32];
#pragma unroll
    for (int i = 0; i < 32; ++i) acc[i] = 0.f;
    for (int k = 0; k < KNN; ++k) {
      int idx = sidx[(r << 4) + k];
      float w = sw[(r << 4) + k];
      const float4* src = (const float4*)(xTb + (size_t)idx * CCH + (cg << 5));
#pragma unroll
      for (int u = 0; u < 8; ++u) {
        float4 v = src[u];
        acc[u * 4 + 0] += w * v.x;
        acc[u * 4 + 1] += w * v.y;
        acc[u * 4 + 2] += w * v.z;
        acc[u * 4 + 3] += w * v.w;
      }
    }
#pragma unroll
    for (int u = 0; u < 8; ++u)
      *(float4*)&agg[r][(cg << 5) + (u << 2)] =
          make_float4(acc[u * 4], acc[u * 4 + 1], acc[u * 4 + 2], acc[u * 4 + 3]);
  }
  __syncthreads();
  // GEMM: thread = (rg, og) computes rows {rg, rg+16, rg+32, rg+48} x outs og*8..+8
  int rg = threadIdx.x >> 4, og = threadIdx.x & 15;
  float accg[4][8];
#pragma unroll
  for (int i = 0; i < 4; ++i)
#pragma unroll
    for (int j = 0; j < 8; ++j) accg[i][j] = 0.f;
  for (int cq = 0; cq < 64; ++cq) {
    int c = cq << 2;
    float4 a[4];
    if (c < 128) {
#pragma unroll
      for (int i = 0; i < 4; ++i)
        a[i] = *(const float4*)(xTb + (size_t)(r0 + rg + (i << 4)) * CCH + c);
    } else {
#pragma unroll
      for (int i = 0; i < 4; ++i)
        a[i] = *(const float4*)&agg[rg + (i << 4)][c - 128];
    }
#pragma unroll
    for (int j = 0; j < 8; ++j) {
      float4 wv = *(const float4*)(w1 + (size_t)((og << 3) + j) * 256 + c);
#pragma unroll
      for (int i = 0; i < 4; ++i)
        accg[i][j] += a[i].x * wv.x + a[i].y * wv.y + a[i].z * wv.z + a[i].w * wv.w;
    }
  }
#pragma unroll
  for (int i = 0; i < 4; ++i) {
    int row = r0 + rg + (i << 4);
    float* dst = h_pre + ((size_t)b * NPTS + row) * CCH + (og << 3);
    *(float4*)dst = make_float4(accg[i][0], accg[i][1], accg[i][2], accg[i][3]);
    *(float4*)(dst + 4) = make_float4(accg[i][4], accg[i][5], accg[i][6], accg[i][7]);
  }
#pragma unroll
  for (int j = 0; j < 8; ++j) {
    float ps = accg[0][j] + accg[1][j] + accg[2][j] + accg[3][j];
    float pq = accg[0][j] * accg[0][j] + accg[1][j] * accg[1][j] +
               accg[2][j] * accg[2][j] + accg[3][j] * accg[3][j];
    atomicAdd(&sred[(og << 3) + j], ps);
    atomicAdd(&sred[128 + (og << 3) + j], pq);
  }
  __syncthreads();
  atomicAdd(&stats1[threadIdx.x], sred[threadIdx.x]);
}

// ---------------- K4: BN1+ReLU + GEMM2 + BN2 stats ----------------
__global__ __launch_bounds__(256) void k_gemm2(const float* __restrict__ h_pre,
                                               const float* __restrict__ stats1,
                                               const float* __restrict__ g1,
                                               const float* __restrict__ b1,
                                               const float* __restrict__ w2,
                                               float* __restrict__ y_pre,
                                               float* __restrict__ stats2) {
  __shared__ float hl[64][132];
  __shared__ float sred[256];
  int b = blockIdx.x >> 7;
  int r0 = (blockIdx.x & 127) << 6;
  sred[threadIdx.x] = 0.f;
  {
    int c = threadIdx.x & 127;
    float sm = stats1[c] * (1.f / 16384.f);
    float sq = stats1[128 + c] * (1.f / 16384.f);
    float var = fmaxf(sq - sm * sm, 0.f);
    float sc = g1[c] * rsqrtf(var + 1e-5f);
    float sh = b1[c] - sm * sc;
    for (int r = threadIdx.x >> 7; r < 64; r += 2) {
      float v = h_pre[((size_t)b * NPTS + r0 + r) * CCH + c];
      hl[r][c] = fmaxf(v * sc + sh, 0.f);
    }
  }
  __syncthreads();
  int rg = threadIdx.x >> 4, og = threadIdx.x & 15;
  float accg[4][8];
#pragma unroll
  for (int i = 0; i < 4; ++i)
#pragma unroll
    for (int j = 0; j < 8; ++j) accg[i][j] = 0.f;
  for (int cq = 0; cq < 32; ++cq) {
    int c = cq << 2;
    float4 a[4];
#pragma unroll
    for (int i = 0; i < 4; ++i) a[i] = *(const float4*)&hl[rg + (i << 4)][c];
#pragma unroll
    for (int j = 0; j < 8; ++j) {
      float4 wv = *(const float4*)(w2 + (size_t)((og << 3) + j) * CCH + c);
#pragma unroll
      for (int i = 0; i < 4; ++i)
        accg[i][j] += a[i].x * wv.x + a[i].y * wv.y + a[i].z * wv.z + a[i].w * wv.w;
    }
  }
#pragma unroll
  for (int i = 0; i < 4; ++i) {
    int row = r0 + rg + (i << 4);
    float* dst = y_pre + ((size_t)b * NPTS + row) * CCH + (og << 3);
    *(float4*)dst = make_float4(accg[i][0], accg[i][1], accg[i][2], accg[i][3]);
    *(float4*)(dst + 4) = make_float4(accg[i][4], accg[i][5], accg[i][6], accg[i][7]);
  }
#pragma unroll
  for (int j = 0; j < 8; ++j) {
    float ps = accg[0][j] + accg[1][j] + accg[2][j] + accg[3][j];
    float pq = accg[0][j] * accg[0][j] + accg[1][j] * accg[1][j] +
               accg[2][j] * accg[2][j] + accg[3][j] * accg[3][j];
    atomicAdd(&sred[(og << 3) + j], ps);
    atomicAdd(&sred[128 + (og << 3) + j], pq);
  }
  __syncthreads();
  atomicAdd(&stats2[threadIdx.x], sred[threadIdx.x]);
}

// ---------------- K6: SE pool: s_sum[b][c] = sum_n relu(bn2(y_pre)) ----------
__global__ __launch_bounds__(256) void k_sepool(const float* __restrict__ y_pre,
                                                const float* __restrict__ stats2,
                                                const float* __restrict__ g2,
                                                const float* __restrict__ b2,
                                                float* __restrict__ s_sum) {
  __shared__ float red[256];
  int b = blockIdx.x >> 5;
  int r0 = (blockIdx.x & 31) << 8;
  int c = threadIdx.x & 127, half = threadIdx.x >> 7;
  float sm = stats2[c] * (1.f / 16384.f);
  float sq = stats2[128 + c] * (1.f / 16384.f);
  float var = fmaxf(sq - sm * sm, 0.f);
  float sc = g2[c] * rsqrtf(var + 1e-5f);
  float sh = b2[c] - sm * sc;
  float acc = 0.f;
  for (int r = half; r < 256; r += 2) {
    float v = y_pre[((size_t)b * NPTS + r0 + r) * CCH + c];
    acc += fmaxf(v * sc + sh, 0.f);
  }
  red[threadIdx.x] = acc;
  __syncthreads();
  if (half == 0) atomicAdd(&s_sum[b * CCH + c], red[c] + red[128 + c]);
}

// ---------------- K7: SE gate (tiny) ----------------
__global__ __launch_bounds__(128) void k_segate(const float* __restrict__ s_sum,
                                                const float* __restrict__ fc1w,
                                                const float* __restrict__ fc1b,
                                                const float* __restrict__ fc2w,
                                                const float* __restrict__ fc2b,
                                                float* __restrict__ gate) {
  __shared__ float s[128];
  __shared__ float hid[8];
  int b = blockIdx.x, t = threadIdx.x;
  s[t] = s_sum[b * CCH + t] * (1.f / 8192.f);
  __syncthreads();
  if (t < 8) {
    float a = fc1b[t];
    for (int c = 0; c < 128; ++c) a += s[c] * fc1w[t * 128 + c];
    hid[t] = fmaxf(a, 0.f);
  }
  __syncthreads();
  float a = fc2b[t];
#pragma unroll
  for (int j = 0; j < 8; ++j) a += hid[j] * fc2w[t * 8 + j];
  gate[b * CCH + t] = 1.f / (1.f + __expf(-a));
}

// ---------------- K8: bn2+relu+gate + residual + transpose to [B,C,N] --------
__global__ __launch_bounds__(256) void k_out(const float* __restrict__ x,
                                             const float* __restrict__ y_pre,
                                             const float* __restrict__ stats2,
                                             const float* __restrict__ g2,
                                             const float* __restrict__ b2,
                                             const float* __restrict__ gate,
                                             float* __restrict__ out) {
  __shared__ float t[64][129];
  int b = blockIdx.x >> 7;
  int n0 = (blockIdx.x & 127) << 6;
  {
    int c = threadIdx.x & 127;
    float sm = stats2[c] * (1.f / 16384.f);
    float sq = stats2[128 + c] * (1.f / 16384.f);
    float var = fmaxf(sq - sm * sm, 0.f);
    float sc = g2[c] * rsqrtf(var + 1e-5f);
    float sh = b2[c] - sm * sc;
    float gt = gate[b * CCH + c];
    for (int r = threadIdx.x >> 7; r < 64; r += 2) {
      float v = y_pre[((size_t)b * NPTS + n0 + r) * CCH + c];
      t[r][c] = fmaxf(v * sc + sh, 0.f) * gt;
    }
  }
  __syncthreads();
  int nl = threadIdx.x & 63, cg = threadIdx.x >> 6;
  for (int cc = cg; cc < CCH; cc += 4) {
    size_t o = ((size_t)b * CCH + cc) * NPTS + n0 + nl;
    out[o] = x[o] + t[nl][cc];
  }
}

extern "C" void kernel_launch(void* const* d_in, const int* in_sizes, int n_in,
                              void* d_out, int out_size, void* d_ws, size_t ws_size,
                              hipStream_t stream) {
  const float* x = (const float*)d_in[0];
  const float* pos = (const float*)d_in[1];
  const float* w1 = (const float*)d_in[2];
  const float* g1 = (const float*)d_in[3];
  const float* b1 = (const float*)d_in[4];
  const float* w2 = (const float*)d_in[5];
  const float* g2 = (const float*)d_in[6];
  const float* b2 = (const float*)d_in[7];
  const float* fc1w = (const float*)d_in[8];
  const float* fc1b = (const float*)d_in[9];
  const float* fc2w = (const float*)d_in[10];
  const float* fc2b = (const float*)d_in[11];
  float* out = (float*)d_out;
  char* ws = (char*)d_ws;

  float* xT = (float*)(ws + 0);                   //  8 MB
  int* nn_idx = (int*)(ws + 8388608);             //  2 MB
  float* nn_w = (float*)(ws + 10485760);          //  2 MB
  float* h_pre = (float*)(ws + 12582912);         //  8 MB
  float* y_pre = (float*)(ws + 20971520);         //  8 MB
  float* stats1 = (float*)(ws + 29360128);        //  1 KB  (sum[128], sumsq[128])
  float* stats2 = (float*)(ws + 29361152);        //  1 KB
  float* s_sum = (float*)(ws + 29362176);         //  1 KB
  float* gate = (float*)(ws + 29363200);          //  1 KB

  hipMemsetAsync(ws + 29360128, 0, 4096, stream);

  k_transpose<<<1024, 256, 0, stream>>>(x, xT);
  k_knn<<<1024, 512, 0, stream>>>(pos, nn_idx, nn_w);
  k_gemm1<<<256, 256, 0, stream>>>(xT, nn_idx, nn_w, w1, h_pre, stats1);
  k_gemm2<<<256, 256, 0, stream>>>(h_pre, stats1, g1, b1, w2, y_pre, stats2);
  k_sepool<<<64, 256, 0, stream>>>(y_pre, stats2, g2, b2, s_sum);
  k_segate<<<2, 128, 0, stream>>>(s_sum, fc1w, fc1b, fc2w, fc2b, gate);
  k_out<<<256, 256, 0, stream>>>(x, y_pre, stats2, g2, b2, gate, out);
}

// Round 4
// 252.753 us; speedup vs baseline: 1.4228x; 1.1544x over previous
//
#include <hip/hip_runtime.h>
#include <math.h>

#define NPTS 8192
#define NB 2
#define CCH 128
#define KNN 16

// ---------------- K-1: zero the stats block (replaces hipMemsetAsync) -------
__global__ __launch_bounds__(256) void k_zero(float* __restrict__ p) {
  p[blockIdx.x * 256 + threadIdx.x] = 0.f;
}

// ---------------- K0: transpose x [B,C,N] -> xT [B,N,C] ----------------
__global__ __launch_bounds__(256) void k_transpose(const float* __restrict__ x,
                                                   float* __restrict__ xT) {
  __shared__ float t[32][65];
  int blk = blockIdx.x;
  int b = blk >> 9;             // 512 tiles per batch: 4 c-tiles x 128 n-tiles
  int rem = blk & 511;
  int c0 = (rem >> 7) << 5;
  int n0 = (rem & 127) << 6;
  const float* xb = x + (size_t)b * CCH * NPTS;
  float* xTb = xT + (size_t)b * NPTS * CCH;
  int nj = threadIdx.x & 63, ci = threadIdx.x >> 6;
#pragma unroll
  for (int i = 0; i < 8; ++i) {
    int c = ci * 8 + i;
    t[c][nj] = xb[(size_t)(c0 + c) * NPTS + n0 + nj];
  }
  __syncthreads();
  int cl = threadIdx.x & 31, nl = threadIdx.x >> 5;
#pragma unroll
  for (int i = 0; i < 8; ++i) {
    int n = nl * 8 + i;
    xTb[(size_t)(n0 + n) * CCH + c0 + cl] = t[cl][n];
  }
}

// ---------------- K1: KNN, 2 queries per wave, scalar drains ----------------
#define SWZI(v, imm) __builtin_amdgcn_ds_swizzle((v), (imm))
#define SWZF(v, imm) __int_as_float(__builtin_amdgcn_ds_swizzle(__float_as_int(v), (imm)))

#define BSTAGE(K, J, IMM)                                          \
  {                                                                \
    float od = SWZF(sd, IMM);                                      \
    int oi = SWZI(si, IMM);                                        \
    bool up = ((sub & (K)) == 0);                                  \
    bool lower = ((sub & (J)) == 0);                               \
    bool take = lower ? ((sd > od) == up) : ((sd < od) == up);     \
    if (take) { sd = od; si = oi; }                                \
  }

__global__ __launch_bounds__(512, 8) void k_knn(const float* __restrict__ pos,
                                                int* __restrict__ nn_idx,
                                                float* __restrict__ nn_w) {
  __shared__ float4 cpos[2048];                   // 32 KB chunk: (x,y,z,|p|^2)
  const int b = blockIdx.x >> 9;                  // 512 blocks per batch
  const int wid = threadIdx.x >> 6;
  const int lane = threadIdx.x & 63;
  const int sub = lane & 31;
  const int grp = lane >> 5;
  const int q = ((blockIdx.x & 511) << 4) + (wid << 1) + grp;
  const float* px = pos + (size_t)b * 3 * NPTS;
  const float* py = px + NPTS;
  const float* pz = py + NPTS;
  const float qx = px[q], qy = py[q], qz = pz[q];
  const float n2qx = -2.f * qx, n2qy = -2.f * qy, n2qz = -2.f * qz;
  const float qsq = fmaf(qx, qx, fmaf(qy, qy, qz * qz));
  const bool holder = (sub < 16);
  const int addrUp = (lane == 0 ? 0 : (lane - 1)) << 2;
  const int addrT = ((lane & 32) | 15) << 2;

  float bd = 3.4e38f;
  int bi = 0;
  float Tv = 3.4e38f;

  for (int ch = 0; ch < 4; ++ch) {
    __syncthreads();
    for (int i = threadIdx.x; i < 2048; i += 512) {
      int j = (ch << 11) + i;
      float x = px[j], y = py[j], z = pz[j];
      cpos[i] = make_float4(x, y, z, fmaf(x, x, fmaf(y, y, z * z)));
    }
    __syncthreads();
    int t0 = 0;
    if (ch == 0) {
      float4 cp = cpos[sub];
      float sd = fmaf(cp.z, n2qz, fmaf(cp.y, n2qy, fmaf(cp.x, n2qx, cp.w + qsq)));
      int si = sub;
      BSTAGE(2, 1, 0x041F)
      BSTAGE(4, 2, 0x081F)  BSTAGE(4, 1, 0x041F)
      BSTAGE(8, 4, 0x101F)  BSTAGE(8, 2, 0x081F)  BSTAGE(8, 1, 0x041F)
      BSTAGE(16, 8, 0x201F) BSTAGE(16, 4, 0x101F) BSTAGE(16, 2, 0x081F) BSTAGE(16, 1, 0x041F)
      BSTAGE(32, 16, 0x401F) BSTAGE(32, 8, 0x201F) BSTAGE(32, 4, 0x101F) BSTAGE(32, 2, 0x081F) BSTAGE(32, 1, 0x041F)
      bd = holder ? sd : 3.4e38f;
      bi = si;
      Tv = __int_as_float(__builtin_amdgcn_ds_bpermute(addrT, __float_as_int(bd)));
      t0 = 1;
    }
    for (int t = t0; t < 64; ++t) {
      float4 cp = cpos[(t << 5) + sub];
      float d2 = fmaf(cp.z, n2qz, fmaf(cp.y, n2qy, fmaf(cp.x, n2qx, cp.w + qsq)));
      unsigned long long m = __ballot(d2 < Tv);
      if (m) {
        int cb = (ch << 11) + (t << 5);
        unsigned int mA = (unsigned int)m;
        unsigned int mB = (unsigned int)(m >> 32);
        while (mA) {
          int l = __builtin_ctz(mA);
          mA &= mA - 1;
          float v = __int_as_float(__builtin_amdgcn_readlane(__float_as_int(d2), l));
          int vi = cb + l;
          bool gt = (lane < 16) && (bd > v);
          unsigned long long bm = __ballot(gt);
          float ud = __int_as_float(__builtin_amdgcn_ds_bpermute(addrUp, __float_as_int(bd)));
          int ui = __builtin_amdgcn_ds_bpermute(addrUp, bi);
          bool first = (sub == 0) || !(((bm << 1) >> lane) & 1);
          if (gt) {
            bd = first ? v : ud;
            bi = first ? vi : ui;
          }
        }
        while (mB) {
          int l = __builtin_ctz(mB);
          mB &= mB - 1;
          float v = __int_as_float(__builtin_amdgcn_readlane(__float_as_int(d2), l + 32));
          int vi = cb + l;
          bool gt = (lane >= 32) && (lane < 48) && (bd > v);
          unsigned long long bm = __ballot(gt);
          float ud = __int_as_float(__builtin_amdgcn_ds_bpermute(addrUp, __float_as_int(bd)));
          int ui = __builtin_amdgcn_ds_bpermute(addrUp, bi);
          bool first = (sub == 0) || !(((bm << 1) >> lane) & 1);
          if (gt) {
            bd = first ? v : ud;
            bi = first ? vi : ui;
          }
        }
        Tv = __int_as_float(__builtin_amdgcn_ds_bpermute(addrT, __float_as_int(bd)));
      }
    }
  }
  float nx = px[bi], ny = py[bi], nz = pz[bi];
  float dx = qx - nx, dy = qy - ny, dz = qz - nz;
  float dd = fmaxf(sqrtf(fmaf(dx, dx, fmaf(dy, dy, dz * dz))), 1e-6f);
  float logit = -dd * 5.0f;
  float mx = holder ? logit : -3.4e38f;
  mx = fmaxf(mx, SWZF(mx, 0x041F));
  mx = fmaxf(mx, SWZF(mx, 0x081F));
  mx = fmaxf(mx, SWZF(mx, 0x101F));
  mx = fmaxf(mx, SWZF(mx, 0x201F));
  float e = holder ? __expf(logit - mx) : 0.f;   // mask non-holders out of the sum
  float s = e;
  s += SWZF(s, 0x041F);
  s += SWZF(s, 0x081F);
  s += SWZF(s, 0x101F);
  s += SWZF(s, 0x201F);
  if (holder) {
    size_t o = ((size_t)b * NPTS + q) * KNN + sub;
    nn_idx[o] = bi;
    nn_w[o] = e / s;
  }
}

// ---------------- K2a: neighbor aggregation, one wave per point ----------------
__global__ __launch_bounds__(256) void k_agg(const float* __restrict__ xT,
                                             const int* __restrict__ nn_idx,
                                             const float* __restrict__ nn_w,
                                             float* __restrict__ agg) {
  int gw = blockIdx.x * 4 + (threadIdx.x >> 6);   // 0..16383 (= b*NPTS+n)
  int lane = threadIdx.x & 63;
  const float* xTb = xT + (size_t)(gw >> 13) * NPTS * CCH;
  size_t o = (size_t)gw * KNN;
  float ax = 0.f, ay = 0.f;
#pragma unroll
  for (int k = 0; k < KNN; ++k) {
    int idx = nn_idx[o + k];
    float w = nn_w[o + k];
    float2 v = *(const float2*)(xTb + (size_t)idx * CCH + (lane << 1));
    ax = fmaf(w, v.x, ax);
    ay = fmaf(w, v.y, ay);
  }
  *(float2*)(agg + (size_t)gw * CCH + (lane << 1)) = make_float2(ax, ay);
}

// ---------------- K2b: GEMM1 h = fuse[32x256] x w1^T + BN1 stats ----------------
__global__ __launch_bounds__(256) void k_gemm1(const float* __restrict__ xT,
                                               const float* __restrict__ agg,
                                               const float* __restrict__ w1,
                                               float* __restrict__ h_pre,
                                               float* __restrict__ stats1) {
  __shared__ float alds[32][68];
  __shared__ float wlds[128][68];
  __shared__ float sred[256];
  int b = blockIdx.x >> 8;
  int r0 = (blockIdx.x & 255) << 5;
  const float* xTb = xT + (size_t)b * NPTS * CCH;
  const float* aggb = agg + (size_t)b * NPTS * CCH;
  int rg = threadIdx.x & 7, og = threadIdx.x >> 3;
  float acc[4][4];
#pragma unroll
  for (int i = 0; i < 4; ++i)
#pragma unroll
    for (int j = 0; j < 4; ++j) acc[i][j] = 0.f;
  sred[threadIdx.x] = 0.f;
  for (int ch = 0; ch < 4; ++ch) {
    __syncthreads();
#pragma unroll
    for (int it = 0; it < 2; ++it) {        // stage A: 32 x 64
      int i = threadIdx.x + it * 256;
      int r = i >> 4, kq = i & 15;
      const float* src = (ch < 2)
          ? (xTb + (size_t)(r0 + r) * CCH + (ch << 6) + (kq << 2))
          : (aggb + (size_t)(r0 + r) * CCH + ((ch - 2) << 6) + (kq << 2));
      *(float4*)&alds[r][kq << 2] = *(const float4*)src;
    }
#pragma unroll
    for (int it = 0; it < 8; ++it) {        // stage W: 128 x 64
      int i = threadIdx.x + it * 256;
      int h = i >> 4, kq = i & 15;
      *(float4*)&wlds[h][kq << 2] =
          *(const float4*)(w1 + (size_t)h * 256 + (ch << 6) + (kq << 2));
    }
    __syncthreads();
#pragma unroll
    for (int cq = 0; cq < 16; ++cq) {
      int c = cq << 2;
      float4 a[4], w[4];
#pragma unroll
      for (int i = 0; i < 4; ++i) a[i] = *(const float4*)&alds[rg + (i << 3)][c];
#pragma unroll
      for (int j = 0; j < 4; ++j) w[j] = *(const float4*)&wlds[og + (j << 5)][c];
#pragma unroll
      for (int i = 0; i < 4; ++i)
#pragma unroll
        for (int j = 0; j < 4; ++j)
          acc[i][j] += a[i].x * w[j].x + a[i].y * w[j].y + a[i].z * w[j].z + a[i].w * w[j].w;
    }
  }
#pragma unroll
  for (int i = 0; i < 4; ++i) {
    int row = r0 + rg + (i << 3);
    float* dst = h_pre + ((size_t)b * NPTS + row) * CCH;
#pragma unroll
    for (int j = 0; j < 4; ++j) dst[og + (j << 5)] = acc[i][j];
  }
#pragma unroll
  for (int j = 0; j < 4; ++j) {
    float ps = acc[0][j] + acc[1][j] + acc[2][j] + acc[3][j];
    float pq = acc[0][j] * acc[0][j] + acc[1][j] * acc[1][j] +
               acc[2][j] * acc[2][j] + acc[3][j] * acc[3][j];
    atomicAdd(&sred[og + (j << 5)], ps);
    atomicAdd(&sred[128 + og + (j << 5)], pq);
  }
  __syncthreads();
  atomicAdd(&stats1[threadIdx.x], sred[threadIdx.x]);
}

// ---------------- K4: BN1+ReLU + GEMM2 + BN2 stats ----------------
__global__ __launch_bounds__(256) void k_gemm2(const float* __restrict__ h_pre,
                                               const float* __restrict__ stats1,
                                               const float* __restrict__ g1,
                                               const float* __restrict__ b1,
                                               const float* __restrict__ w2,
                                               float* __restrict__ y_pre,
                                               float* __restrict__ stats2) {
  __shared__ float alds[32][68];
  __shared__ float wlds[128][68];
  __shared__ float sred[256];
  __shared__ float scs[128], shs[128];
  int b = blockIdx.x >> 8;
  int r0 = (blockIdx.x & 255) << 5;
  int rg = threadIdx.x & 7, og = threadIdx.x >> 3;
  float acc[4][4];
#pragma unroll
  for (int i = 0; i < 4; ++i)
#pragma unroll
    for (int j = 0; j < 4; ++j) acc[i][j] = 0.f;
  sred[threadIdx.x] = 0.f;
  if (threadIdx.x < 128) {
    int c = threadIdx.x;
    float sm = stats1[c] * (1.f / 16384.f);
    float sq = stats1[128 + c] * (1.f / 16384.f);
    float var = fmaxf(sq - sm * sm, 0.f);
    float sc = g1[c] * rsqrtf(var + 1e-5f);
    scs[c] = sc;
    shs[c] = b1[c] - sm * sc;
  }
  for (int ch = 0; ch < 2; ++ch) {
    __syncthreads();
#pragma unroll
    for (int it = 0; it < 2; ++it) {        // stage A = relu(bn1(h_pre)) 32 x 64
      int i = threadIdx.x + it * 256;
      int r = i >> 4, kq = i & 15;
      int c = (ch << 6) + (kq << 2);
      float4 v = *(const float4*)(h_pre + ((size_t)b * NPTS + r0 + r) * CCH + c);
      float4 sc = *(const float4*)&scs[c];
      float4 sh = *(const float4*)&shs[c];
      v.x = fmaxf(fmaf(v.x, sc.x, sh.x), 0.f);
      v.y = fmaxf(fmaf(v.y, sc.y, sh.y), 0.f);
      v.z = fmaxf(fmaf(v.z, sc.z, sh.z), 0.f);
      v.w = fmaxf(fmaf(v.w, sc.w, sh.w), 0.f);
      *(float4*)&alds[r][kq << 2] = v;
    }
#pragma unroll
    for (int it = 0; it < 8; ++it) {        // stage W2: 128 x 64
      int i = threadIdx.x + it * 256;
      int h = i >> 4, kq = i & 15;
      *(float4*)&wlds[h][kq << 2] =
          *(const float4*)(w2 + (size_t)h * CCH + (ch << 6) + (kq << 2));
    }
    __syncthreads();
#pragma unroll
    for (int cq = 0; cq < 16; ++cq) {
      int c = cq << 2;
      float4 a[4], w[4];
#pragma unroll
      for (int i = 0; i < 4; ++i) a[i] = *(const float4*)&alds[rg + (i << 3)][c];
#pragma unroll
      for (int j = 0; j < 4; ++j) w[j] = *(const float4*)&wlds[og + (j << 5)][c];
#pragma unroll
      for (int i = 0; i < 4; ++i)
#pragma unroll
        for (int j = 0; j < 4; ++j)
          acc[i][j] += a[i].x * w[j].x + a[i].y * w[j].y + a[i].z * w[j].z + a[i].w * w[j].w;
    }
  }
#pragma unroll
  for (int i = 0; i < 4; ++i) {
    int row = r0 + rg + (i << 3);
    float* dst = y_pre + ((size_t)b * NPTS + row) * CCH;
#pragma unroll
    for (int j = 0; j < 4; ++j) dst[og + (j << 5)] = acc[i][j];
  }
#pragma unroll
  for (int j = 0; j < 4; ++j) {
    float ps = acc[0][j] + acc[1][j] + acc[2][j] + acc[3][j];
    float pq = acc[0][j] * acc[0][j] + acc[1][j] * acc[1][j] +
               acc[2][j] * acc[2][j] + acc[3][j] * acc[3][j];
    atomicAdd(&sred[og + (j << 5)], ps);
    atomicAdd(&sred[128 + og + (j << 5)], pq);
  }
  __syncthreads();
  atomicAdd(&stats2[threadIdx.x], sred[threadIdx.x]);
}

// ---------------- K6: SE pool ----------------
__global__ __launch_bounds__(256) void k_sepool(const float* __restrict__ y_pre,
                                                const float* __restrict__ stats2,
                                                const float* __restrict__ g2,
                                                const float* __restrict__ b2,
                                                float* __restrict__ s_sum) {
  __shared__ float red[256];
  int b = blockIdx.x >> 5;
  int r0 = (blockIdx.x & 31) << 8;
  int c = threadIdx.x & 127, half = threadIdx.x >> 7;
  float sm = stats2[c] * (1.f / 16384.f);
  float sq = stats2[128 + c] * (1.f / 16384.f);
  float var = fmaxf(sq - sm * sm, 0.f);
  float sc = g2[c] * rsqrtf(var + 1e-5f);
  float sh = b2[c] - sm * sc;
  float acc = 0.f;
  for (int r = half; r < 256; r += 2) {
    float v = y_pre[((size_t)b * NPTS + r0 + r) * CCH + c];
    acc += fmaxf(v * sc + sh, 0.f);
  }
  red[threadIdx.x] = acc;
  __syncthreads();
  if (half == 0) atomicAdd(&s_sum[b * CCH + c], red[c] + red[128 + c]);
}

// ---------------- K7: SE gate ----------------
__global__ __launch_bounds__(128) void k_segate(const float* __restrict__ s_sum,
                                                const float* __restrict__ fc1w,
                                                const float* __restrict__ fc1b,
                                                const float* __restrict__ fc2w,
                                                const float* __restrict__ fc2b,
                                                float* __restrict__ gate) {
  __shared__ float s[128];
  __shared__ float hid[8];
  int b = blockIdx.x, t = threadIdx.x;
  s[t] = s_sum[b * CCH + t] * (1.f / 8192.f);
  __syncthreads();
  if (t < 8) {
    float a = fc1b[t];
    for (int c = 0; c < 128; ++c) a += s[c] * fc1w[t * 128 + c];
    hid[t] = fmaxf(a, 0.f);
  }
  __syncthreads();
  float a = fc2b[t];
#pragma unroll
  for (int j = 0; j < 8; ++j) a += hid[j] * fc2w[t * 8 + j];
  gate[b * CCH + t] = 1.f / (1.f + __expf(-a));
}

// ---------------- K8: bn2+relu+gate + residual + transpose ----------------
__global__ __launch_bounds__(256) void k_out(const float* __restrict__ x,
                                             const float* __restrict__ y_pre,
                                             const float* __restrict__ stats2,
                                             const float* __restrict__ g2,
                                             const float* __restrict__ b2,
                                             const float* __restrict__ gate,
                                             float* __restrict__ out) {
  __shared__ float t[64][129];
  int b = blockIdx.x >> 7;
  int n0 = (blockIdx.x & 127) << 6;
  {
    int c = threadIdx.x & 127;
    float sm = stats2[c] * (1.f / 16384.f);
    float sq = stats2[128 + c] * (1.f / 16384.f);
    float var = fmaxf(sq - sm * sm, 0.f);
    float sc = g2[c] * rsqrtf(var + 1e-5f);
    float sh = b2[c] - sm * sc;
    float gt = gate[b * CCH + c];
    for (int r = threadIdx.x >> 7; r < 64; r += 2) {
      float v = y_pre[((size_t)b * NPTS + n0 + r) * CCH + c];
      t[r][c] = fmaxf(v * sc + sh, 0.f) * gt;
    }
  }
  __syncthreads();
  int nl = threadIdx.x & 63, cg = threadIdx.x >> 6;
  for (int cc = cg; cc < CCH; cc += 4) {
    size_t o = ((size_t)b * CCH + cc) * NPTS + n0 + nl;
    out[o] = x[o] + t[nl][cc];
  }
}

extern "C" void kernel_launch(void* const* d_in, const int* in_sizes, int n_in,
                              void* d_out, int out_size, void* d_ws, size_t ws_size,
                              hipStream_t stream) {
  const float* x = (const float*)d_in[0];
  const float* pos = (const float*)d_in[1];
  const float* w1 = (const float*)d_in[2];
  const float* g1 = (const float*)d_in[3];
  const float* b1 = (const float*)d_in[4];
  const float* w2 = (const float*)d_in[5];
  const float* g2 = (const float*)d_in[6];
  const float* b2 = (const float*)d_in[7];
  const float* fc1w = (const float*)d_in[8];
  const float* fc1b = (const float*)d_in[9];
  const float* fc2w = (const float*)d_in[10];
  const float* fc2b = (const float*)d_in[11];
  float* out = (float*)d_out;
  char* ws = (char*)d_ws;
  const size_t MB = 1048576;

  // Layout. Preferred (ws >= 34MB+4KB): fully disjoint buffers.
  // Fallback: y_pre aliases xT (xT dead after k_gemm1; rewritten by
  // k_transpose at the start of every call before any reader).
  float* xT = (float*)(ws + 0);             //  8 MB [B,N,128]
  int* nn_idx = (int*)(ws + 8 * MB);        //  1 MB
  float* nn_w = (float*)(ws + 9 * MB);      //  1 MB
  float* agg = (float*)(ws + 10 * MB);      //  8 MB [B,N,128]
  float* h_pre = (float*)(ws + 18 * MB);    //  8 MB
  float* y_pre;
  float* stats;
  if (ws_size >= 34 * MB + 4096) {
    y_pre = (float*)(ws + 26 * MB);         //  8 MB (disjoint)
    stats = (float*)(ws + 34 * MB);
  } else {
    y_pre = (float*)(ws + 0);               //  aliases xT
    stats = (float*)(ws + 26 * MB);
  }
  float* stats1 = stats;                    // 256 floats: sum[128], sumsq[128]
  float* stats2 = stats + 256;
  float* s_sum = stats + 512;
  float* gate = stats + 768;

  k_zero<<<4, 256, 0, stream>>>(stats);     // zero stats1/stats2/s_sum/gate
  k_transpose<<<1024, 256, 0, stream>>>(x, xT);
  k_knn<<<1024, 512, 0, stream>>>(pos, nn_idx, nn_w);
  k_agg<<<4096, 256, 0, stream>>>(xT, nn_idx, nn_w, agg);
  k_gemm1<<<512, 256, 0, stream>>>(xT, agg, w1, h_pre, stats1);
  k_gemm2<<<512, 256, 0, stream>>>(h_pre, stats1, g1, b1, w2, y_pre, stats2);
  k_sepool<<<64, 256, 0, stream>>>(y_pre, stats2, g2, b2, s_sum);
  k_segate<<<2, 128, 0, stream>>>(s_sum, fc1w, fc1b, fc2w, fc2b, gate);
  k_out<<<256, 256, 0, stream>>>(x, y_pre, stats2, g2, b2, gate, out);
}